// Round 10
// baseline (835.749 us; speedup 1.0000x reference)
//
#include <hip/hip_runtime.h>

namespace {

constexpr float kDT = 1e-3f;
constexpr int kB = 512;
constexpr int kT = 8192;
constexpr int kThr = 256;                 // 4 waves per block
constexpr int kChunk = kThr * 2;          // 512 steps per chunk
constexpr int kNC = kT / kChunk;          // 16 chunks per row
constexpr int kWaves = kThr / 64;         // 4
constexpr int kBlocks = kB * kNC;         // 8192

// Affine transform x' = M x + b packed {a,b,c,d,p,q}
struct Xf { float a, b, c, d, p, q; };

// Apply e (earlier) first, then l (later).
__device__ __forceinline__ Xf comp(const Xf& e, const Xf& l) {
  Xf o;
  o.a = l.a * e.a + l.b * e.c;
  o.b = l.a * e.b + l.b * e.d;
  o.c = l.c * e.a + l.d * e.c;
  o.d = l.c * e.b + l.d * e.d;
  o.p = l.a * e.p + l.b * e.q + l.p;
  o.q = l.c * e.p + l.d * e.q + l.q;
  return o;
}

__device__ __forceinline__ Xf shfl_up_xf(const Xf& v, int d) {
  Xf r;
  r.a = __shfl_up(v.a, d); r.b = __shfl_up(v.b, d);
  r.c = __shfl_up(v.c, d); r.d = __shfl_up(v.d, d);
  r.p = __shfl_up(v.p, d); r.q = __shfl_up(v.q, d);
  return r;
}

__device__ __forceinline__ Xf make_xf(const float4 xv, float d0, float d1,
                                      float A00, float A01, float A10, float A11,
                                      float C00, float C01, float C10, float C11) {
  Xf m;
  m.a = 1.0f + kDT * (A00 - (xv.x * C00 + xv.y * C10));
  m.b =        kDT * (A01 - (xv.x * C01 + xv.y * C11));
  m.c =        kDT * (A10 - (xv.z * C00 + xv.w * C10));
  m.d = 1.0f + kDT * (A11 - (xv.z * C01 + xv.w * C11));
  m.p = xv.x * d0 + xv.y * d1;
  m.q = xv.z * d0 + xv.w * d1;
  return m;
}

// Single pass, dispatch-order-safe decoupled lookback:
//  - ticket assigns virtual block IDs in actual start order (no deadlock
//    under undefined dispatch order: we only wait on already-started blocks)
//  - compute chunk aggregate, publish (release), thread-0 lookback, emit.
__global__ __launch_bounds__(kThr) void k_scan_emit(
    const float* __restrict__ xic, const float* __restrict__ dy,
    const float* __restrict__ Ap, const float* __restrict__ Cp,
    float* __restrict__ agg, unsigned int* __restrict__ flag,
    unsigned int* __restrict__ ticket, float* __restrict__ out) {
  __shared__ float sWT[kWaves][6];
  __shared__ float sE[2];
  __shared__ unsigned int sVb;

  const int tid = threadIdx.x;
  const int lane = tid & 63;
  const int w = tid >> 6;

  if (tid == 0) {
    sVb = __hip_atomic_fetch_add(ticket, 1u, __ATOMIC_RELAXED,
                                 __HIP_MEMORY_SCOPE_AGENT);
  }
  __syncthreads();
  const int blk = (int)sVb;            // virtual block id, start-ordered
  const int r = blk / kNC;
  const int c = blk % kNC;
  const size_t step0 = (size_t)blk * kChunk + 2 * tid;

  const float4* X4 = reinterpret_cast<const float4*>(xic);
  const float4* D4 = reinterpret_cast<const float4*>(dy);
  float4* O4 = reinterpret_cast<float4*>(out);
  float4* A4 = reinterpret_cast<float4*>(agg);   // 2 float4 per block (32B)

  const float4 xv0 = X4[step0];
  const float4 xv1 = X4[step0 + 1];
  const float4 dv = D4[step0 >> 1];

  const float A00 = Ap[0], A01 = Ap[1], A10 = Ap[2], A11 = Ap[3];
  const float C00 = Cp[0], C01 = Cp[1], C10 = Cp[2], C11 = Cp[3];

  const Xf s0 = make_xf(xv0, dv.x, dv.y, A00, A01, A10, A11, C00, C01, C10, C11);
  const Xf s1 = make_xf(xv1, dv.z, dv.w, A00, A01, A10, A11, C00, C01, C10, C11);
  const Xf tt = comp(s0, s1);

  // Wave inclusive shuffle scan over thread totals (lane order = step order).
  Xf inc = tt;
#pragma unroll
  for (int d = 1; d < 64; d <<= 1) {
    const Xf rr = shfl_up_xf(inc, d);
    if (lane >= d) inc = comp(rr, inc);
  }
  if (lane == 63) {
    sWT[w][0] = inc.a; sWT[w][1] = inc.b; sWT[w][2] = inc.c;
    sWT[w][3] = inc.d; sWT[w][4] = inc.p; sWT[w][5] = inc.q;
  }
  __syncthreads();

  // Thread 0: publish aggregate, then sequential lookback over predecessors.
  if (tid == 0) {
    Xf t{sWT[0][0], sWT[0][1], sWT[0][2], sWT[0][3], sWT[0][4], sWT[0][5]};
    for (int i = 1; i < kWaves; ++i) {
      const Xf wt{sWT[i][0], sWT[i][1], sWT[i][2],
                  sWT[i][3], sWT[i][4], sWT[i][5]};
      t = comp(t, wt);
    }
    A4[2 * blk]     = make_float4(t.a, t.b, t.c, t.d);
    A4[2 * blk + 1] = make_float4(t.p, t.q, 0.f, 0.f);
    __threadfence();
    __hip_atomic_store(&flag[blk], 1u, __ATOMIC_RELEASE,
                       __HIP_MEMORY_SCOPE_AGENT);

    float e0 = 1.0f, e1 = 0.0f;  // row-initial state (1,0)
    if (c > 0) {
      Xf pre{1.f, 0.f, 0.f, 1.f, 0.f, 0.f};
      const int base = r * kNC;
      for (int i = 0; i < c; ++i) {
        while (__hip_atomic_load(&flag[base + i], __ATOMIC_ACQUIRE,
                                 __HIP_MEMORY_SCOPE_AGENT) == 0u) {
          __builtin_amdgcn_s_sleep(1);
        }
        const float4 m01 = A4[2 * (base + i)];
        const float4 m23 = A4[2 * (base + i) + 1];
        const Xf ti{m01.x, m01.y, m01.z, m01.w, m23.x, m23.y};
        pre = comp(pre, ti);
      }
      e0 = pre.a + pre.p;
      e1 = pre.c + pre.q;
    }
    sE[0] = e0; sE[1] = e1;
  }
  __syncthreads();

  const float e0 = sE[0], e1 = sE[1];

  // Wave-exclusive prefix (redundant per-thread, <=3 composes from LDS).
  Xf Ew{1.f, 0.f, 0.f, 1.f, 0.f, 0.f};
  for (int i = 0; i < w; ++i) {
    const Xf wt{sWT[i][0], sWT[i][1], sWT[i][2],
                sWT[i][3], sWT[i][4], sWT[i][5]};
    Ew = comp(Ew, wt);
  }
  Xf le = shfl_up_xf(inc, 1);
  if (lane == 0) le = Xf{1.f, 0.f, 0.f, 1.f, 0.f, 0.f};
  const Xf ex = comp(Ew, le);  // block-exclusive prefix for this thread

  // State entering this thread's first step.
  const float x0 = ex.a * e0 + ex.b * e1 + ex.p;
  const float x1 = ex.c * e0 + ex.d * e1 + ex.q;

  float4 o;
  o.x = kDT * (C00 * x0 + C01 * x1);
  o.y = kDT * (C10 * x0 + C11 * x1);
  const float t0 = s0.a * x0 + s0.b * x1 + s0.p;
  const float t1 = s0.c * x0 + s0.d * x1 + s0.q;
  o.z = kDT * (C00 * t0 + C01 * t1);
  o.w = kDT * (C10 * t0 + C11 * t1);
  O4[step0 >> 1] = o;
}

}  // namespace

extern "C" void kernel_launch(void* const* d_in, const int* in_sizes, int n_in,
                              void* d_out, int out_size, void* d_ws,
                              size_t ws_size, hipStream_t stream) {
  const float* xic = (const float*)d_in[0];  // [B,T,2,2]
  const float* dy  = (const float*)d_in[1];  // [B,T,2]
  const float* Ap  = (const float*)d_in[2];  // [2,2] coeffs_A
  const float* Cp  = (const float*)d_in[3];  // [2,2] C
  float* out = (float*)d_out;                // [B,T,2]

  // ws layout: agg (kBlocks * 8 floats, 32B-aligned) | flags | ticket
  float* agg = (float*)d_ws;                                   // 256 KiB
  unsigned int* flag = (unsigned int*)(agg + (size_t)kBlocks * 8);  // 32 KiB
  unsigned int* ticket = flag + kBlocks;                       // 4 B

  // Zero flags + ticket every launch (stream-ordered, graph-capturable).
  hipMemsetAsync(flag, 0, (kBlocks + 1) * sizeof(unsigned int), stream);

  k_scan_emit<<<kBlocks, kThr, 0, stream>>>(xic, dy, Ap, Cp, agg, flag,
                                            ticket, out);
}

// Round 11
// 42.259 us; speedup vs baseline: 19.7769x; 19.7769x over previous
//
#include <hip/hip_runtime.h>

namespace {

constexpr float kDT = 1e-3f;
constexpr int kB = 512;
constexpr int kT = 8192;
constexpr int kThreads = 1024;
constexpr int kWaves = kThreads / 64;     // 16
constexpr int kPassSteps = 2 * kThreads;  // 2048 steps per pass
constexpr int kPasses = kT / kPassSteps;  // 4

// Affine transform x' = M x + b packed {a,b,c,d,p,q}
struct Xf { float a, b, c, d, p, q; };

// Apply e (earlier) first, then l (later).
__device__ __forceinline__ Xf comp(const Xf& e, const Xf& l) {
  Xf o;
  o.a = l.a * e.a + l.b * e.c;
  o.b = l.a * e.b + l.b * e.d;
  o.c = l.c * e.a + l.d * e.c;
  o.d = l.c * e.b + l.d * e.d;
  o.p = l.a * e.p + l.b * e.q + l.p;
  o.q = l.c * e.p + l.d * e.q + l.q;
  return o;
}

__device__ __forceinline__ Xf shfl_up_xf(const Xf& v, int d) {
  Xf r;
  r.a = __shfl_up(v.a, d); r.b = __shfl_up(v.b, d);
  r.c = __shfl_up(v.c, d); r.d = __shfl_up(v.d, d);
  r.p = __shfl_up(v.p, d); r.q = __shfl_up(v.q, d);
  return r;
}

__device__ __forceinline__ Xf shfl_xf(const Xf& v, int src) {
  Xf r;
  r.a = __shfl(v.a, src); r.b = __shfl(v.b, src);
  r.c = __shfl(v.c, src); r.d = __shfl(v.d, src);
  r.p = __shfl(v.p, src); r.q = __shfl(v.q, src);
  return r;
}

__device__ __forceinline__ Xf make_xf(const float4 xv, float d0, float d1,
                                      float A00, float A01, float A10, float A11,
                                      float C00, float C01, float C10, float C11) {
  Xf m;
  m.a = 1.0f + kDT * (A00 - (xv.x * C00 + xv.y * C10));
  m.b =        kDT * (A01 - (xv.x * C01 + xv.y * C11));
  m.c =        kDT * (A10 - (xv.z * C00 + xv.w * C10));
  m.d = 1.0f + kDT * (A11 - (xv.z * C01 + xv.w * C11));
  m.p = xv.x * d0 + xv.y * d1;
  m.q = xv.z * d0 + xv.w * d1;
  return m;
}

// One block per batch row; 4 passes of 2048 steps; 2 consecutive steps per
// thread. ONE barrier per pass: wave totals go to double-buffered LDS, then
// every wave redundantly scans the 16 totals in lanes 0..15 (shuffle) and
// broadcasts its exclusive prefix + pass total via shfl. No wave idles.
__global__ __launch_bounds__(kThreads) void k_fused(
    const float* __restrict__ xic, const float* __restrict__ dy,
    const float* __restrict__ Ap, const float* __restrict__ Cp,
    float* __restrict__ out) {
  __shared__ float sWT[2][kWaves][6];

  const int tid = threadIdx.x;
  const int lane = tid & 63;
  const int w = tid >> 6;
  const size_t rbase = (size_t)blockIdx.x * kT;        // in steps (xic float4s)
  const size_t rbase2 = (size_t)blockIdx.x * (kT / 2); // in float4s of dy/out

  const float4* X4 = reinterpret_cast<const float4*>(xic);
  const float4* D4 = reinterpret_cast<const float4*>(dy);
  float4* O4 = reinterpret_cast<float4*>(out);

  const float A00 = Ap[0], A01 = Ap[1], A10 = Ap[2], A11 = Ap[3];
  const float C00 = Cp[0], C01 = Cp[1], C10 = Cp[2], C11 = Cp[3];

  float4 xva[2], xvb[2], dva[2];

  // Prefetch pass 0.
  {
    const size_t s = (size_t)2 * tid;
    xva[0] = X4[rbase + s];
    xvb[0] = X4[rbase + s + 1];
    dva[0] = D4[rbase2 + tid];
  }

  float x0 = 1.0f, x1 = 0.0f;  // row state entering current pass

#pragma unroll
  for (int c = 0; c < kPasses; ++c) {
    const int buf = c & 1;
    // Prefetch next pass before any barrier/scan of this pass.
    if (c + 1 < kPasses) {
      const size_t s = (size_t)(c + 1) * kPassSteps + 2 * tid;
      xva[buf ^ 1] = X4[rbase + s];
      xvb[buf ^ 1] = X4[rbase + s + 1];
      dva[buf ^ 1] = D4[rbase2 + (size_t)(c + 1) * kThreads + tid];
    }

    // Per-step transforms for this thread's 2 steps.
    const Xf s0 = make_xf(xva[buf], dva[buf].x, dva[buf].y,
                          A00, A01, A10, A11, C00, C01, C10, C11);
    const Xf s1 = make_xf(xvb[buf], dva[buf].z, dva[buf].w,
                          A00, A01, A10, A11, C00, C01, C10, C11);
    const Xf tot = comp(s0, s1);

    // Wave-level inclusive shuffle scan over thread totals.
    Xf inc = tot;
#pragma unroll
    for (int d = 1; d < 64; d <<= 1) {
      const Xf r = shfl_up_xf(inc, d);
      if (lane >= d) inc = comp(r, inc);
    }

    if (lane == 63) {
      sWT[buf][w][0] = inc.a; sWT[buf][w][1] = inc.b; sWT[buf][w][2] = inc.c;
      sWT[buf][w][3] = inc.d; sWT[buf][w][4] = inc.p; sWT[buf][w][5] = inc.q;
    }
    __syncthreads();  // the ONLY barrier this pass

    // Every wave: lanes 0..15 hold the 16 wave totals, 4-round shuffle scan.
    Xf v{1.f, 0.f, 0.f, 1.f, 0.f, 0.f};
    if (lane < kWaves) {
      v = Xf{sWT[buf][lane][0], sWT[buf][lane][1], sWT[buf][lane][2],
             sWT[buf][lane][3], sWT[buf][lane][4], sWT[buf][lane][5]};
    }
#pragma unroll
    for (int d = 1; d < kWaves; d <<= 1) {
      const Xf r = shfl_up_xf(v, d);
      if (lane >= d && lane < kWaves) v = comp(r, v);
    }
    // Broadcast pass total and this wave's exclusive prefix to all lanes.
    const Xf TT = shfl_xf(v, kWaves - 1);
    Xf Ew{1.f, 0.f, 0.f, 1.f, 0.f, 0.f};
    if (w > 0) Ew = shfl_xf(v, w - 1);

    // Lane-exclusive prefix within the wave.
    Xf le = shfl_up_xf(inc, 1);
    if (lane == 0) le = Xf{1.f, 0.f, 0.f, 1.f, 0.f, 0.f};

    const Xf ex = comp(Ew, le);  // block-exclusive prefix for this thread

    // State entering this thread's first step.
    const float e0 = ex.a * x0 + ex.b * x1 + ex.p;
    const float e1 = ex.c * x0 + ex.d * x1 + ex.q;

    // Emit 2 outputs (pre-update state), advance through s0.
    float4 o;
    o.x = kDT * (C00 * e0 + C01 * e1);
    o.y = kDT * (C10 * e0 + C11 * e1);
    const float t0 = s0.a * e0 + s0.b * e1 + s0.p;
    const float t1 = s0.c * e0 + s0.d * e1 + s0.q;
    o.z = kDT * (C00 * t0 + C01 * t1);
    o.w = kDT * (C10 * t0 + C11 * t1);
    O4[rbase2 + (size_t)c * kThreads + tid] = o;

    // Advance row state by the whole pass (identical in all threads).
    if (c + 1 < kPasses) {
      const float n0 = TT.a * x0 + TT.b * x1 + TT.p;
      const float n1 = TT.c * x0 + TT.d * x1 + TT.q;
      x0 = n0; x1 = n1;
    }
  }
}

}  // namespace

extern "C" void kernel_launch(void* const* d_in, const int* in_sizes, int n_in,
                              void* d_out, int out_size, void* d_ws,
                              size_t ws_size, hipStream_t stream) {
  const float* xic = (const float*)d_in[0];  // [B,T,2,2]
  const float* dy  = (const float*)d_in[1];  // [B,T,2]
  const float* Ap  = (const float*)d_in[2];  // [2,2] coeffs_A
  const float* Cp  = (const float*)d_in[3];  // [2,2] C
  float* out = (float*)d_out;                // [B,T,2]

  k_fused<<<kB, kThreads, 0, stream>>>(xic, dy, Ap, Cp, out);
}

// Round 12
// 30.232 us; speedup vs baseline: 27.6445x; 1.3978x over previous
//
#include <hip/hip_runtime.h>

namespace {

constexpr float kDT = 1e-3f;
constexpr int kB = 512;
constexpr int kT = 8192;
constexpr int kThreads = 1024;
constexpr int kWaves = kThreads / 64;     // 16
constexpr int kPassSteps = 2 * kThreads;  // 2048 steps per pass
constexpr int kPasses = kT / kPassSteps;  // 4

// Affine transform x' = M x + b packed {a,b,c,d,p,q}
struct Xf { float a, b, c, d, p, q; };

// Apply e (earlier) first, then l (later).
__device__ __forceinline__ Xf comp(const Xf& e, const Xf& l) {
  Xf o;
  o.a = l.a * e.a + l.b * e.c;
  o.b = l.a * e.b + l.b * e.d;
  o.c = l.c * e.a + l.d * e.c;
  o.d = l.c * e.b + l.d * e.d;
  o.p = l.a * e.p + l.b * e.q + l.p;
  o.q = l.c * e.p + l.d * e.q + l.q;
  return o;
}

// DPP move with per-component identity fallback: lanes whose source is
// invalid (bound_ctrl=false) or masked off by RowMask keep `old`.
template <int Ctrl, int RowMask>
__device__ __forceinline__ float dpp1(float v, float old) {
  return __int_as_float(__builtin_amdgcn_update_dpp(
      __float_as_int(old), __float_as_int(v), Ctrl, RowMask, 0xf, false));
}

// Shifted transform with identity in invalid/masked lanes -> compose is
// unconditionally safe (comp(I, x) == x). Pure VALU, no LDS.
template <int Ctrl, int RowMask>
__device__ __forceinline__ Xf dpp_xf(const Xf& v) {
  Xf r;
  r.a = dpp1<Ctrl, RowMask>(v.a, 1.0f);
  r.b = dpp1<Ctrl, RowMask>(v.b, 0.0f);
  r.c = dpp1<Ctrl, RowMask>(v.c, 0.0f);
  r.d = dpp1<Ctrl, RowMask>(v.d, 1.0f);
  r.p = dpp1<Ctrl, RowMask>(v.p, 0.0f);
  r.q = dpp1<Ctrl, RowMask>(v.q, 0.0f);
  return r;
}

// Canonical GCN wave64 inclusive scan: row_shr 1/2/4/8, bcast15 -> rows 1&3,
// bcast31 -> rows 2&3. 36 v_mov_dpp total, zero DS ops.
__device__ __forceinline__ Xf wave_incl_scan(Xf x) {
  x = comp(dpp_xf<0x111, 0xf>(x), x);  // row_shr:1
  x = comp(dpp_xf<0x112, 0xf>(x), x);  // row_shr:2
  x = comp(dpp_xf<0x114, 0xf>(x), x);  // row_shr:4
  x = comp(dpp_xf<0x118, 0xf>(x), x);  // row_shr:8
  x = comp(dpp_xf<0x142, 0xa>(x), x);  // row_bcast:15 -> rows 1,3
  x = comp(dpp_xf<0x143, 0xc>(x), x);  // row_bcast:31 -> rows 2,3
  return x;
}

__device__ __forceinline__ Xf readlane_xf(const Xf& v, int l) {
  Xf r;
  r.a = __int_as_float(__builtin_amdgcn_readlane(__float_as_int(v.a), l));
  r.b = __int_as_float(__builtin_amdgcn_readlane(__float_as_int(v.b), l));
  r.c = __int_as_float(__builtin_amdgcn_readlane(__float_as_int(v.c), l));
  r.d = __int_as_float(__builtin_amdgcn_readlane(__float_as_int(v.d), l));
  r.p = __int_as_float(__builtin_amdgcn_readlane(__float_as_int(v.p), l));
  r.q = __int_as_float(__builtin_amdgcn_readlane(__float_as_int(v.q), l));
  return r;
}

__device__ __forceinline__ Xf make_xf(const float4 xv, float d0, float d1,
                                      float A00, float A01, float A10, float A11,
                                      float C00, float C01, float C10, float C11) {
  Xf m;
  m.a = 1.0f + kDT * (A00 - (xv.x * C00 + xv.y * C10));
  m.b =        kDT * (A01 - (xv.x * C01 + xv.y * C11));
  m.c =        kDT * (A10 - (xv.z * C00 + xv.w * C10));
  m.d = 1.0f + kDT * (A11 - (xv.z * C01 + xv.w * C11));
  m.p = xv.x * d0 + xv.y * d1;
  m.q = xv.z * d0 + xv.w * d1;
  return m;
}

// One block per batch row; 4 passes of 2048 steps; 2 consecutive steps per
// thread (R7's proven memory pattern). All scans on the VALU via DPP; LDS
// used only for 16 wave totals (double-buffered, 1 barrier per pass).
__global__ __launch_bounds__(kThreads) void k_fused(
    const float* __restrict__ xic, const float* __restrict__ dy,
    const float* __restrict__ Ap, const float* __restrict__ Cp,
    float* __restrict__ out) {
  __shared__ float sWT[2][kWaves][6];

  const int tid = threadIdx.x;
  const int lane = tid & 63;
  const int w = tid >> 6;
  const size_t rbase = (size_t)blockIdx.x * kT;        // xic float4 index
  const size_t rbase2 = (size_t)blockIdx.x * (kT / 2); // dy/out float4 index

  const float4* X4 = reinterpret_cast<const float4*>(xic);
  const float4* D4 = reinterpret_cast<const float4*>(dy);
  float4* O4 = reinterpret_cast<float4*>(out);

  const float A00 = Ap[0], A01 = Ap[1], A10 = Ap[2], A11 = Ap[3];
  const float C00 = Cp[0], C01 = Cp[1], C10 = Cp[2], C11 = Cp[3];

  float4 xva[2], xvb[2], dva[2];

  // Prefetch pass 0.
  {
    const size_t s = (size_t)2 * tid;
    xva[0] = X4[rbase + s];
    xvb[0] = X4[rbase + s + 1];
    dva[0] = D4[rbase2 + tid];
  }

  float x0 = 1.0f, x1 = 0.0f;  // row state entering current pass

#pragma unroll
  for (int c = 0; c < kPasses; ++c) {
    const int buf = c & 1;
    // Prefetch next pass before any barrier/scan of this pass.
    if (c + 1 < kPasses) {
      const size_t s = (size_t)(c + 1) * kPassSteps + 2 * tid;
      xva[buf ^ 1] = X4[rbase + s];
      xvb[buf ^ 1] = X4[rbase + s + 1];
      dva[buf ^ 1] = D4[rbase2 + (size_t)(c + 1) * kThreads + tid];
    }

    // Per-step transforms for this thread's 2 steps.
    const Xf s0 = make_xf(xva[buf], dva[buf].x, dva[buf].y,
                          A00, A01, A10, A11, C00, C01, C10, C11);
    const Xf s1 = make_xf(xvb[buf], dva[buf].z, dva[buf].w,
                          A00, A01, A10, A11, C00, C01, C10, C11);
    const Xf tot = comp(s0, s1);

    // Wave-level inclusive scan over thread totals (pure VALU/DPP).
    const Xf inc = wave_incl_scan(tot);

    if (lane == 63) {
      sWT[buf][w][0] = inc.a; sWT[buf][w][1] = inc.b; sWT[buf][w][2] = inc.c;
      sWT[buf][w][3] = inc.d; sWT[buf][w][4] = inc.p; sWT[buf][w][5] = inc.q;
    }
    __syncthreads();  // the only barrier this pass (sWT double-buffered)

    // Every wave redundantly: lanes 0..15 read the 16 wave totals
    // (conflict-free: stride 6 dwords), 4-round DPP scan, readlane bcast.
    Xf v{1.f, 0.f, 0.f, 1.f, 0.f, 0.f};
    if (lane < kWaves) {
      v = Xf{sWT[buf][lane][0], sWT[buf][lane][1], sWT[buf][lane][2],
             sWT[buf][lane][3], sWT[buf][lane][4], sWT[buf][lane][5]};
    }
    v = comp(dpp_xf<0x111, 0xf>(v), v);
    v = comp(dpp_xf<0x112, 0xf>(v), v);
    v = comp(dpp_xf<0x114, 0xf>(v), v);
    v = comp(dpp_xf<0x118, 0xf>(v), v);

    const Xf TT = readlane_xf(v, kWaves - 1);           // pass total
    Xf Ew{1.f, 0.f, 0.f, 1.f, 0.f, 0.f};
    if (w > 0) Ew = readlane_xf(v, w - 1);              // wave-uniform branch

    // Lane-exclusive prefix: whole-wave shift right by 1 (WF_SR1).
    const Xf le = dpp_xf<0x138, 0xf>(inc);              // lane0 -> identity

    const Xf ex = comp(Ew, le);  // block-exclusive prefix for this thread

    // State entering this thread's first step.
    const float e0 = ex.a * x0 + ex.b * x1 + ex.p;
    const float e1 = ex.c * x0 + ex.d * x1 + ex.q;

    // Emit 2 outputs (pre-update state), advance through s0.
    float4 o;
    o.x = kDT * (C00 * e0 + C01 * e1);
    o.y = kDT * (C10 * e0 + C11 * e1);
    const float t0 = s0.a * e0 + s0.b * e1 + s0.p;
    const float t1 = s0.c * e0 + s0.d * e1 + s0.q;
    o.z = kDT * (C00 * t0 + C01 * t1);
    o.w = kDT * (C10 * t0 + C11 * t1);
    O4[rbase2 + (size_t)c * kThreads + tid] = o;

    // Advance row state by the whole pass (identical in all threads).
    if (c + 1 < kPasses) {
      const float n0 = TT.a * x0 + TT.b * x1 + TT.p;
      const float n1 = TT.c * x0 + TT.d * x1 + TT.q;
      x0 = n0; x1 = n1;
    }
  }
}

}  // namespace

extern "C" void kernel_launch(void* const* d_in, const int* in_sizes, int n_in,
                              void* d_out, int out_size, void* d_ws,
                              size_t ws_size, hipStream_t stream) {
  const float* xic = (const float*)d_in[0];  // [B,T,2,2]
  const float* dy  = (const float*)d_in[1];  // [B,T,2]
  const float* Ap  = (const float*)d_in[2];  // [2,2] coeffs_A
  const float* Cp  = (const float*)d_in[3];  // [2,2] C
  float* out = (float*)d_out;                // [B,T,2]

  k_fused<<<kB, kThreads, 0, stream>>>(xic, dy, Ap, Cp, out);
}